// Round 8
// baseline (176.613 us; speedup 1.0000x reference)
//
#include <hip/hip_runtime.h>

// grid [2,160,160,160,3] fp32; interior 156^3 per batch.
#define OY 480
#define OX 76800
#define SB 12288000
#define ZP 56                    // z-stride per row (52 interior + 4 halo)
#define CP 952                   // comp-plane stride: 17 rows * ZP
#define SLICE 2856               // 3 comps * CP
#define NBUF 6                   // ring depth (matches 6x unroll; 1 barrier/step)
#define NBLK 504                 // 2 b * 12 jt * 3 kt * 7 iseg
#define INV_SIZE (1.0f/22778496.0f)

#define LD8(dst, p)  { *(float4*)(dst) = *(const float4*)(p); \
                       *(float4*)((dst)+4) = *(const float4*)((p)+4); }
#define LD4Z(dst, p) { *(float2*)(dst) = *(const float2*)((p)+2); \
                       *(float2*)((dst)+2) = *(const float2*)((p)+4); }

// Tile: 13 j-rows x 52 z, marching 24 (or 12) i-slices. LDS = 6-slice ring,
// SoA [comp][row][z]. Staging threads read 12 consecutive global floats,
// transpose AoS->SoA in registers, write 3 contiguous b128 (conflict-free).
// Own-row (j) windows live in a register pipeline across the 6x-unrolled
// march: hzz/hxx/hxz need no LDS reads at all.
__global__ __launch_bounds__(256, 2)
void be_partials(const float* __restrict__ g, float* __restrict__ partial) {
    __shared__ float lds[NBUF * SLICE];
    __shared__ float wsum[4];

    const int tid  = threadIdx.x;
    const int bid  = blockIdx.x;
    const int iseg = bid % 7;
    int r_ = bid / 7;
    const int kt = r_ % 3;  r_ /= 3;
    const int jt = r_ % 12;
    const int bb = r_ / 12;
    const int j0  = jt * 13;              // staged rows j0..j0+16
    const int kf0 = kt * 156;             // z-window start (floats)
    const int i0  = iseg * 24;            // i0 % 6 == 0
    const int len = (iseg == 6) ? 12 : 24;

    const float* __restrict__ G = g + (size_t)bb * SB;

    // ---- staging mapping: 238 threads x 12 consecutive floats (4 z-pts) ----
    const bool stg = tid < 238;
    int srow = 0, st14 = 0;
    if (stg) { srow = tid / 14; st14 = tid - srow * 14; }
    const int goff = (j0 + srow) * OY + kf0 + 12 * st14;
    const int lw   = srow * ZP + 4 * st14;          // + c*CP

    // ---- compute mapping: 169 threads = 13 rows x 13 z-strips of 4 ----
    const bool act = tid < 169;                     // (R7 bug: was 156)
    int jj = act ? tid / 13 : 0;
    int ss = act ? tid - jj * 13 : 0;
    const int rbase = (jj + 2) * ZP + 4 * ss;       // comp0 own-row window base

    // own-row register pipeline
    float a0[6][8], a1[3][8], a2[3][8];

    // ---- warmup: stage slices i0..i0+4 (ring slot = w since i0%6==0) ----
    for (int w = 0; w < 5; ++w) {
        if (stg) {
            const float* base = G + (size_t)(i0 + w) * OX + goff;
            float4 q0 = *(const float4*)(base);
            float4 q1 = *(const float4*)(base + 4);
            float4 q2 = *(const float4*)(base + 8);
            float* L = lds + w * SLICE + lw;
            *(float4*)(L)        = make_float4(q0.x, q0.w, q1.z, q2.y);
            *(float4*)(L + CP)   = make_float4(q0.y, q1.x, q1.w, q2.z);
            *(float4*)(L + 2*CP) = make_float4(q0.z, q1.y, q2.x, q2.w);
        }
    }
    __syncthreads();
    if (act) {
        #pragma unroll
        for (int s = 0; s < 4; ++s) LD8(a0[s], lds + s * SLICE + rbase);
        #pragma unroll
        for (int s = 1; s <= 2; ++s) {
            LD8(a1[s], lds + s * SLICE + CP + rbase);
            LD8(a2[s], lds + s * SLICE + 2*CP + rbase);
        }
    }

    float w1 = 0.f, w2 = 0.f, w3 = 0.f, w4 = 0.f;
    for (int tb = 0; tb < len; tb += 6) {
        #pragma unroll
        for (int U = 0; U < 6; ++U) {
            const int t  = tb + U;
            const int cg = i0 + 2 + t;            // absolute center slice
            const bool doLoad = (t < len - 1);
            float4 q0, q1, q2;
            if (doLoad && stg) {                   // prefetch slice cg+3
                const float* base = G + (size_t)(cg + 3) * OX + goff;
                q0 = *(const float4*)(base);
                q1 = *(const float4*)(base + 4);
                q2 = *(const float4*)(base + 8);
            }

            if (act) {
                // static ring/pipeline indices (fold after unroll)
                const int sc   = (2 + U) % 6;      // slot & a0 idx: slice cg
                const int sp1  = (3 + U) % 6;      // cg+1
                const int sp2  = (4 + U) % 6;      // cg+2
                const int sm1  = (1 + U) % 6;      // cg-1
                const int sm2  = (U) % 6;          // cg-2
                const int ic   = (2 + U) % 3;      // a1/a2 idx: slice cg
                const int ip1  = (U) % 3;          // cg+1 (loaded now)
                const int im1  = (1 + U) % 3;      // cg-1

                // pipeline loads: comp0 of cg+2; comp1,2 of cg+1
                LD8(a0[sp2], lds + sp2 * SLICE + rbase);
                LD8(a1[ip1], lds + sp1 * SLICE + CP + rbase);
                LD8(a2[ip1], lds + sp1 * SLICE + 2*CP + rbase);

                const float* S1 = lds + sm1 * SLICE;
                const float* S2 = lds + sc  * SLICE;
                const float* S3 = lds + sp1 * SLICE;

                const float* A0c = a0[sc];  const float* A0p = a0[sp1];
                const float* A0m = a0[sm1]; const float* A0P = a0[sp2];
                const float* A0M = a0[sm2];
                const float* A1c = a1[ic];  const float* A1p = a1[ip1];
                const float* A1m = a1[im1];
                const float* A2c = a2[ic];  const float* A2p = a2[ip1];
                const float* A2m = a2[im1];

                // ---- register-resident stencils ----
                #pragma unroll
                for (int q = 0; q < 4; ++q) {
                    float hzz0 = A0c[q+4] - 2.f*A0c[q+2] + A0c[q];
                    float hzz1 = A1c[q+4] - 2.f*A1c[q+2] + A1c[q];
                    float hzz2 = A2c[q+4] - 2.f*A2c[q+2] + A2c[q];
                    w2 = fmaf(hzz0, hzz0, w2);
                    w2 = fmaf(hzz1, hzz1, w2);
                    w1 = fmaf(hzz2, hzz2, w1);
                    float hxx0 = A0P[q+2] - 2.f*A0c[q+2] + A0M[q+2];
                    w1 = fmaf(hxx0, hxx0, w1);
                    float hxz0 = (A0p[q+3] - A0p[q+1]) - (A0m[q+3] - A0m[q+1]);
                    float hxz1 = (A1p[q+3] - A1p[q+1]) - (A1m[q+3] - A1m[q+1]);
                    float hxz2 = (A2p[q+3] - A2p[q+1]) - (A2m[q+3] - A2m[q+1]);
                    w3 = fmaf(hxz0, hxz0, w3);
                    w2 = fmaf(hxz1, hxz1, w2);
                    w1 = fmaf(hxz2, hxz2, w1);
                }
                // ---- hyz: rows j+-1, 3 comps, windows ----
                {
                    float P[8], M[8];
                    LD8(P, S2 + rbase + ZP); LD8(M, S2 + rbase - ZP);
                    #pragma unroll
                    for (int q = 0; q < 4; ++q) {
                        float h = (P[q+3] - P[q+1]) - (M[q+3] - M[q+1]);
                        w4 = fmaf(h, h, w4);
                    }
                    LD8(P, S2 + CP + rbase + ZP); LD8(M, S2 + CP + rbase - ZP);
                    #pragma unroll
                    for (int q = 0; q < 4; ++q) {
                        float h = (P[q+3] - P[q+1]) - (M[q+3] - M[q+1]);
                        w3 = fmaf(h, h, w3);
                    }
                    LD8(P, S2 + 2*CP + rbase + ZP); LD8(M, S2 + 2*CP + rbase - ZP);
                    #pragma unroll
                    for (int q = 0; q < 4; ++q) {
                        float h = (P[q+3] - P[q+1]) - (M[q+3] - M[q+1]);
                        w1 = fmaf(h, h, w1);
                    }
                }
                // ---- hyy: rows j+-2, comps 0,1, exact z ----
                {
                    float Pz[4], Mz[4];
                    LD4Z(Pz, S2 + rbase + 2*ZP); LD4Z(Mz, S2 + rbase - 2*ZP);
                    #pragma unroll
                    for (int q = 0; q < 4; ++q) {
                        float h = Pz[q] - 2.f*A0c[q+2] + Mz[q];
                        w2 = fmaf(h, h, w2);
                    }
                    LD4Z(Pz, S2 + CP + rbase + 2*ZP); LD4Z(Mz, S2 + CP + rbase - 2*ZP);
                    #pragma unroll
                    for (int q = 0; q < 4; ++q) {
                        float h = Pz[q] - 2.f*A1c[q+2] + Mz[q];
                        w1 = fmaf(h, h, w1);
                    }
                }
                // ---- hxy: slices x+-1, rows j+-1, comps 0,1, exact z ----
                {
                    float av[4], bv[4], cv[4], dv[4];
                    LD4Z(av, S3 + rbase + ZP); LD4Z(bv, S3 + rbase - ZP);
                    LD4Z(cv, S1 + rbase + ZP); LD4Z(dv, S1 + rbase - ZP);
                    #pragma unroll
                    for (int q = 0; q < 4; ++q) {
                        float h = (av[q] - bv[q]) - (cv[q] - dv[q]);
                        w3 = fmaf(h, h, w3);
                    }
                    LD4Z(av, S3 + CP + rbase + ZP); LD4Z(bv, S3 + CP + rbase - ZP);
                    LD4Z(cv, S1 + CP + rbase + ZP); LD4Z(dv, S1 + CP + rbase - ZP);
                    #pragma unroll
                    for (int q = 0; q < 4; ++q) {
                        float h = (av[q] - bv[q]) - (cv[q] - dv[q]);
                        w1 = fmaf(h, h, w1);
                    }
                }
            }

            if (doLoad && stg) {                   // retire to slot (cg+3)%6
                float* L = lds + ((5 + U) % 6) * SLICE + lw;
                *(float4*)(L)        = make_float4(q0.x, q0.w, q1.z, q2.y);
                *(float4*)(L + CP)   = make_float4(q0.y, q1.x, q1.w, q2.z);
                *(float4*)(L + 2*CP) = make_float4(q0.z, q1.y, q2.x, q2.w);
            }
            __syncthreads();
        }
    }

    float s = fmaf(2.f, w2, w1);
    s = fmaf(3.f, w3, s);
    s = fmaf(4.f, w4, s);
    s *= 0.0625f;

    #pragma unroll
    for (int off = 32; off > 0; off >>= 1) s += __shfl_down(s, off, 64);
    if ((tid & 63) == 0) wsum[tid >> 6] = s;
    __syncthreads();
    if (tid == 0)
        partial[bid] = (wsum[0] + wsum[1]) + (wsum[2] + wsum[3]);
}

__global__ __launch_bounds__(256)
void be_final(const float* __restrict__ partial, float* __restrict__ out) {
    float s = 0.0f;
    for (int i = threadIdx.x; i < NBLK; i += 256) s += partial[i];
    #pragma unroll
    for (int off = 32; off > 0; off >>= 1) s += __shfl_down(s, off, 64);
    __shared__ float ws[4];
    if ((threadIdx.x & 63) == 0) ws[threadIdx.x >> 6] = s;
    __syncthreads();
    if (threadIdx.x == 0)
        out[0] = ((ws[0] + ws[1]) + (ws[2] + ws[3])) * INV_SIZE;
}

extern "C" void kernel_launch(void* const* d_in, const int* in_sizes, int n_in,
                              void* d_out, int out_size, void* d_ws, size_t ws_size,
                              hipStream_t stream) {
    const float* grid = (const float*)d_in[0];
    float* out = (float*)d_out;
    float* partials = (float*)d_ws;               // 504 floats

    be_partials<<<dim3(NBLK), dim3(256), 0, stream>>>(grid, partials);
    be_final<<<1, 256, 0, stream>>>(partials, out);
}